// Round 16
// baseline (757.445 us; speedup 1.0000x reference)
//
#include <hip/hip_runtime.h>
#include <stdint.h>

#define NN 100000   // nodes
#define NE 400000   // edges per relation
#define NR 3        // relations
#define NF 256      // feature dim
#define NK 768      // NR*NF concatenated K
#define NG 128      // graphs
#define SCAN_NB ((NN + 1023) / 1024)   // 98 chunks of 1024
#define NT_GEMM ((NN + 127) / 128)     // 782 row-tiles

typedef __attribute__((ext_vector_type(4))) unsigned short ushortx4;
typedef __attribute__((ext_vector_type(8))) unsigned short ushortx8;
typedef __attribute__((ext_vector_type(8))) short short8;
typedef __attribute__((ext_vector_type(4))) float floatx4;

static __device__ __forceinline__ unsigned short f2bfu(float f) {
  union { float f; uint32_t u; } c; c.f = f;
  uint32_t x = c.u;
  uint32_t r = (x + 0x7fffu + ((x >> 16) & 1u)) >> 16;
  return (unsigned short)r;
}
static __device__ __forceinline__ float bfu2f(unsigned short u) {
  union { uint32_t u; float f; } c; c.u = ((uint32_t)u) << 16;
  return c.f;
}

static __device__ __forceinline__ void gload16(const void* g, void* l) {
  __builtin_amdgcn_global_load_lds(
      (const __attribute__((address_space(1))) uint32_t*)g,
      (__attribute__((address_space(3))) uint32_t*)l, 16, 0, 0);
}

// ---------------- graph preprocessing ----------------

__global__ __launch_bounds__(256) void degree_kernel(
    const int* __restrict__ src, const int* __restrict__ dst,
    int* __restrict__ deg_out, int* __restrict__ deg_in) {
  int t = blockIdx.x * 256 + threadIdx.x;
  int r = blockIdx.y;
  if (t < NE) {
    atomicAdd(&deg_out[r * NN + src[r * NE + t]], 1);
    atomicAdd(&deg_in[r * NN + dst[r * NE + t]], 1);
  }
}

// ---- multi-block exclusive scan of deg_in -> rowptr (3 phases) ----

__global__ __launch_bounds__(256) void scan_phaseA(
    const int* __restrict__ deg_in, int* __restrict__ blocksum) {
  int r = blockIdx.y, b = blockIdx.x, tid = threadIdx.x;
  const int* deg = deg_in + (size_t)r * NN;
  int base = b * 1024 + tid * 4;
  int s = 0;
#pragma unroll
  for (int i = 0; i < 4; ++i) { int idx = base + i; if (idx < NN) s += deg[idx]; }
  __shared__ int red[256];
  red[tid] = s; __syncthreads();
  for (int off = 128; off > 0; off >>= 1) {
    if (tid < off) red[tid] += red[tid + off];
    __syncthreads();
  }
  if (tid == 0) blocksum[r * SCAN_NB + b] = red[0];
}

__global__ __launch_bounds__(128) void scan_phaseB(
    int* __restrict__ blocksum, int* __restrict__ rowptr) {
  int r = blockIdx.x, tid = threadIdx.x;
  int* bs = blocksum + r * SCAN_NB;
  __shared__ int buf[128];
  int v = (tid < SCAN_NB) ? bs[tid] : 0;
  buf[tid] = v; __syncthreads();
  for (int off = 1; off < 128; off <<= 1) {
    int t = (tid >= off) ? buf[tid - off] : 0;
    __syncthreads();
    buf[tid] += t;
    __syncthreads();
  }
  if (tid < SCAN_NB) bs[tid] = buf[tid] - v;   // exclusive chunk offset
  if (tid == 127) rowptr[(size_t)r * (NN + 1) + NN] = buf[127];
}

// phaseC emits rowptr, cursor (copy), and n_dst in one pass
__global__ __launch_bounds__(256) void scan_phaseC(
    const int* __restrict__ deg_in, const int* __restrict__ blocksum,
    int* __restrict__ rowptr, int* __restrict__ cursor,
    float* __restrict__ n_dst) {
  int r = blockIdx.y, b = blockIdx.x, tid = threadIdx.x;
  const int* deg = deg_in + (size_t)r * NN;
  int* rp = rowptr + (size_t)r * (NN + 1);
  int* cp = cursor + (size_t)r * (NN + 1);
  int base = b * 1024 + tid * 4;
  int v[4]; int s = 0;
#pragma unroll
  for (int i = 0; i < 4; ++i) { int idx = base + i; v[i] = (idx < NN) ? deg[idx] : 0; s += v[i]; }
  __shared__ int buf[256];
  buf[tid] = s; __syncthreads();
  for (int off = 1; off < 256; off <<= 1) {
    int t = (tid >= off) ? buf[tid - off] : 0;
    __syncthreads();
    buf[tid] += t;
    __syncthreads();
  }
  int excl = buf[tid] - s + blocksum[r * SCAN_NB + b];
#pragma unroll
  for (int i = 0; i < 4; ++i) {
    int idx = base + i;
    if (idx < NN) {
      rp[idx] = excl;
      cp[idx] = excl;
      n_dst[(size_t)r * NN + idx] = v[i] > 0 ? rsqrtf((float)v[i]) : 0.f;
    }
    excl += v[i];
  }
}

// cursor pre-seeded with rowptr; atomicAdd gives the absolute CSR slot.
// n_src computed on the fly from deg_out (deg_out[s] >= 1 by construction).
__global__ __launch_bounds__(256) void scatter_kernel(
    const int* __restrict__ src, const int* __restrict__ dst,
    int* __restrict__ cursor, const int* __restrict__ deg_out,
    int2* __restrict__ csr_e) {
  int t = blockIdx.x * 256 + threadIdx.x;
  int r = blockIdx.y;
  if (t < NE) {
    int s = src[r * NE + t], v = dst[r * NE + t];
    int pos = atomicAdd(&cursor[r * (NN + 1) + v], 1);   // absolute within relation
    float w = rsqrtf((float)deg_out[r * NN + s]);
    csr_e[(size_t)r * NE + pos] = make_int2(s, __float_as_int(w));
  }
}

// ---------------- weight / feature prep ----------------

// Tiled LDS transpose: W[lay][r][k][n] (f32) -> wt[lay][n][r*256+k] (bf16).
// Also folds the bias sum (bs = b0+b1+b2) into the (tile 0, r 0) blocks.
__global__ __launch_bounds__(256) void prep_w_kernel(
    const float* __restrict__ W1, const float* __restrict__ W2,
    const float* __restrict__ b1, const float* __restrict__ b2,
    unsigned short* __restrict__ wt1, unsigned short* __restrict__ wt2,
    float* __restrict__ bs1, float* __restrict__ bs2) {
  __shared__ float lds[64][65];
  const int tile = blockIdx.x;          // 0..15: (kt,nt) 4x4
  const int r = blockIdx.y;             // 0..2
  const int lay = blockIdx.z;           // 0..1
  const float* W = lay ? W2 : W1;
  unsigned short* wt = lay ? wt2 : wt1;
  const int k0 = (tile >> 2) * 64, n0 = (tile & 3) * 64;
  const int ty = threadIdx.x >> 6;      // 0..3
  const int tx = threadIdx.x & 63;      // 0..63

  if (tile == 0 && r == 0) {            // fused bias sum (one block per layer)
    const float* b = lay ? b2 : b1;
    float* bs = lay ? bs2 : bs1;
    int t = threadIdx.x;
    bs[t] = b[t] + b[NF + t] + b[2 * NF + t];
  }

#pragma unroll
  for (int i = 0; i < 16; ++i) {
    int kl = ty * 16 + i;               // local k row
    lds[kl][tx] = W[((size_t)r * NF + k0 + kl) * NF + n0 + tx];  // coalesced over tx
  }
  __syncthreads();
#pragma unroll
  for (int i = 0; i < 16; ++i) {
    int nl = ty * 16 + i;               // local n row
    wt[(size_t)(n0 + nl) * NK + r * NF + k0 + tx] = f2bfu(lds[tx][nl]);
  }
}

// NT load: feat is read exactly once.
__global__ __launch_bounds__(256) void cast_kernel(
    const float* __restrict__ in, unsigned short* __restrict__ out, int n4) {
  int t = blockIdx.x * 256 + threadIdx.x;
  if (t < n4) {
    floatx4 v = __builtin_nontemporal_load((const floatx4*)&in[(size_t)t * 4]);
    ushortx4 o;
    o.x = f2bfu(v.x); o.y = f2bfu(v.y); o.z = f2bfu(v.z); o.w = f2bfu(v.w);
    *(ushortx4*)&out[(size_t)t * 4] = o;
  }
}

// ---------------- SpMM: one wave per NODE, 3 relations interleaved ----------------
// csr-entry PREFETCH (2-deep); store phase uses ALL 64 lanes (both halves hold
// the shfl_xor sum; lanes>=32 store the upper 4 columns of each strip).

__global__ __launch_bounds__(256) void spmm_kernel(
    const unsigned short* __restrict__ x,   // [NN][256] bf16
    const int* __restrict__ rowptr, const int2* __restrict__ csr_e,
    const float* __restrict__ n_dst,
    unsigned short* __restrict__ agg) {     // [NN][768] bf16
  int wid = threadIdx.x >> 6, l = threadIdx.x & 63;
  int v = blockIdx.x * 4 + wid;
  if (v >= NN) return;
  const int half = l >> 5;        // 0: edge e, 1: edge e+1
  const int c8 = (l & 31) * 8;    // this lane's 8-col strip

  int ea = rowptr[v],                e1a = rowptr[v + 1];
  int eb = rowptr[(NN + 1) + v],     e1b = rowptr[(NN + 1) + v + 1];
  int ec = rowptr[2 * (NN + 1) + v], e1c = rowptr[2 * (NN + 1) + v + 1];
  const int2* cea = csr_e;
  const int2* ceb = csr_e + (size_t)NE;
  const int2* cec = csr_e + (size_t)2 * NE;

  float a[NR][8];
#pragma unroll
  for (int r = 0; r < NR; ++r)
#pragma unroll
    for (int j = 0; j < 8; ++j) a[r][j] = 0.f;

  int2 qa = make_int2(0, 0), qb = make_int2(0, 0), qc = make_int2(0, 0);
  if (ea + half < e1a) qa = cea[ea + half];
  if (eb + half < e1b) qb = ceb[eb + half];
  if (ec + half < e1c) qc = cec[ec + half];

  while (ea < e1a || eb < e1b || ec < e1c) {
    int2 na = make_int2(0, 0), nb = make_int2(0, 0), nc = make_int2(0, 0);
    if (ea + 2 + half < e1a) na = cea[ea + 2 + half];
    if (eb + 2 + half < e1b) nb = ceb[eb + 2 + half];
    if (ec + 2 + half < e1c) nc = cec[ec + 2 + half];

    if (ea < e1a) {
      if (ea + half < e1a) {
        float w = __int_as_float(qa.y);
        ushortx8 xv = *(const ushortx8*)&x[(size_t)qa.x * NF + c8];
#pragma unroll
        for (int j = 0; j < 8; ++j) a[0][j] += w * bfu2f(xv[j]);
      }
      ea += 2; qa = na;
    }
    if (eb < e1b) {
      if (eb + half < e1b) {
        float w = __int_as_float(qb.y);
        ushortx8 xv = *(const ushortx8*)&x[(size_t)qb.x * NF + c8];
#pragma unroll
        for (int j = 0; j < 8; ++j) a[1][j] += w * bfu2f(xv[j]);
      }
      eb += 2; qb = nb;
    }
    if (ec < e1c) {
      if (ec + half < e1c) {
        float w = __int_as_float(qc.y);
        ushortx8 xv = *(const ushortx8*)&x[(size_t)qc.x * NF + c8];
#pragma unroll
        for (int j = 0; j < 8; ++j) a[2][j] += w * bfu2f(xv[j]);
      }
      ec += 2; qc = nc;
    }
  }

#pragma unroll
  for (int r = 0; r < NR; ++r)
#pragma unroll
    for (int j = 0; j < 8; ++j) a[r][j] += __shfl_xor(a[r][j], 32);

  // all-64-lane store: lane l stores 4 cols at (l&31)*8 + (l>>5)*4
  const int j0 = half * 4;
  const int co = c8 + j0;
#pragma unroll
  for (int r = 0; r < NR; ++r) {
    float nd = n_dst[r * NN + v];
    ushortx4 o;
#pragma unroll
    for (int j = 0; j < 4; ++j) o[j] = f2bfu(a[r][j0 + j] * nd);
    *(ushortx4*)&agg[(size_t)v * NK + r * NF + co] = o;
  }
}

// ---------------- GEMM: persistent blocks + tile stealing, counted-vmcnt pipeline ----------------

__global__ __launch_bounds__(256, 2) void gemm_kernel(
    const unsigned short* __restrict__ A,    // [M][768] bf16
    const unsigned short* __restrict__ Bt,   // [256][768] bf16 (B^T: [col][K])
    const float* __restrict__ bias,          // [256]
    unsigned short* __restrict__ C,          // [M][256] bf16
    int M, int relu, int* __restrict__ tilectr) {
  __shared__ unsigned short ldsA[3][128 * 32];   // 24KB
  __shared__ unsigned short ldsB[2][256 * 32];   // 32KB
  __shared__ int s_tile;
  const int tid = threadIdx.x;
  const int l = tid & 63, wid = tid >> 6;
  const int c0 = wid * 64;                    // wave's 64-col strip
  const int fr = l & 15, fk = (l >> 4) * 8;
  const int NKT = NK / 32;                    // 24

  for (;;) {
    if (tid == 0) s_tile = atomicAdd(tilectr, 1);
    __syncthreads();
    const int tile = s_tile;
    if (tile >= NT_GEMM) return;              // uniform exit
    const int row0 = tile * 128;

    floatx4 acc[8][4];
#pragma unroll
    for (int i = 0; i < 8; ++i)
#pragma unroll
      for (int j = 0; j < 4; ++j)
#pragma unroll
        for (int q = 0; q < 4; ++q) acc[i][j][q] = 0.f;

    auto stageA = [&](int b, int kt) {
      const int k0 = kt * 32;
      int u = wid * 64 + l;                   // units 0..255
      int arow = row0 + (u >> 2);
      if (arow >= M) arow = M - 1;
      gload16(A + (size_t)arow * NK + k0 + (u & 3) * 8, &ldsA[b][u * 8]);
      u += 256;                               // units 256..511
      arow = row0 + (u >> 2);
      if (arow >= M) arow = M - 1;
      gload16(A + (size_t)arow * NK + k0 + (u & 3) * 8, &ldsA[b][u * 8]);
    };
    auto stageB = [&](int b, int kt) {
      const int k0 = kt * 32;
#pragma unroll
      for (int p = 0; p < 4; ++p) {           // 1024 units
        int uu = p * 256 + wid * 64 + l;
        gload16(Bt + (size_t)(uu >> 2) * NK + k0 + (uu & 3) * 8, &ldsB[b][uu * 8]);
      }
    };

    // prologue: B(0) [4 loads], A(0) [2], A(1) [2] -> 8 outstanding
    stageB(0, 0);
    stageA(0, 0);
    stageA(1, 1);

    for (int kt = 0; kt < NKT; ++kt) {
      if (kt < NKT - 1) {
        asm volatile("s_waitcnt vmcnt(2)" ::: "memory");
      } else {
        asm volatile("s_waitcnt vmcnt(0)" ::: "memory");
      }
      __builtin_amdgcn_s_barrier();
      __builtin_amdgcn_sched_barrier(0);

      if (kt + 1 < NKT) stageB((kt + 1) & 1, kt + 1);
      if (kt + 2 < NKT) stageA((kt + 2) % 3, kt + 2);
      __builtin_amdgcn_sched_barrier(0);

      const int ba = kt % 3, bb = kt & 1;
      short8 af[8], bf[4];
#pragma unroll
      for (int m = 0; m < 8; ++m)
        af[m] = *(const short8*)&ldsA[ba][(m * 16 + fr) * 32 + fk];
#pragma unroll
      for (int n = 0; n < 4; ++n)
        bf[n] = *(const short8*)&ldsB[bb][(c0 + n * 16 + fr) * 32 + fk];
#pragma unroll
      for (int m = 0; m < 8; ++m)
#pragma unroll
        for (int n = 0; n < 4; ++n)
          acc[m][n] = __builtin_amdgcn_mfma_f32_16x16x32_bf16(af[m], bf[n], acc[m][n], 0, 0, 0);
    }

    const int fq = l >> 4;
#pragma unroll
    for (int m = 0; m < 8; ++m) {
#pragma unroll
      for (int n = 0; n < 4; ++n) {
        int col = c0 + n * 16 + fr;
        float bv = bias[col];
#pragma unroll
        for (int q = 0; q < 4; ++q) {
          int row = row0 + m * 16 + fq * 4 + q;
          if (row < M) {
            float vv = acc[m][n][q] + bv;
            if (relu) vv = fmaxf(vv, 0.f);
            C[(size_t)row * NF + col] = f2bfu(vv);
          }
        }
      }
    }
    __syncthreads();   // all LDS reads done before next tile's stages / s_tile update
  }
}

// ---------------- pooling: one block per graph, no atomics ----------------

__global__ __launch_bounds__(256) void pool_kernel(
    const unsigned short* __restrict__ h2, const int* __restrict__ gid,
    float* __restrict__ out) {
  int g = blockIdx.x, c = threadIdx.x;
  int lo = 0, hi = NN;
  while (lo < hi) { int mid = (lo + hi) >> 1; if (gid[mid] < g) lo = mid + 1; else hi = mid; }
  int a = lo;
  lo = 0; hi = NN;
  while (lo < hi) { int mid = (lo + hi) >> 1; if (gid[mid] < g + 1) lo = mid + 1; else hi = mid; }
  int b = lo;
  float acc = 0.f;
  int v = a;
  for (; v + 4 <= b; v += 4) {
    float t0 = bfu2f(h2[(size_t)(v + 0) * NF + c]);
    float t1 = bfu2f(h2[(size_t)(v + 1) * NF + c]);
    float t2 = bfu2f(h2[(size_t)(v + 2) * NF + c]);
    float t3 = bfu2f(h2[(size_t)(v + 3) * NF + c]);
    acc += t0 + t1 + t2 + t3;
  }
  for (; v < b; ++v) acc += bfu2f(h2[(size_t)v * NF + c]);
  out[g * NF + c] = acc / fmaxf((float)(b - a), 1.f);
}

// ---------------- launch ----------------

extern "C" void kernel_launch(void* const* d_in, const int* in_sizes, int n_in,
                              void* d_out, int out_size, void* d_ws, size_t ws_size,
                              hipStream_t stream) {
  const float* feat = (const float*)d_in[0];
  const int* src = (const int*)d_in[1];
  const int* dst = (const int*)d_in[2];
  const int* gid = (const int*)d_in[3];
  const float* W1 = (const float*)d_in[4];
  const float* b1 = (const float*)d_in[5];
  const float* W2 = (const float*)d_in[6];
  const float* b2 = (const float*)d_in[7];
  float* out = (float*)d_out;

  char* ws = (char*)d_ws;
  size_t off = 0;
  auto alloc = [&](size_t bytes) -> void* {
    void* p = ws + off;
    off = (off + bytes + 255) & ~(size_t)255;
    return p;
  };

  // zero-initialized block (single memset)
  int* deg_out = (int*)alloc((size_t)NR * NN * 4);
  int* deg_in  = (int*)alloc((size_t)NR * NN * 4);
  int* tilectr = (int*)alloc(2 * 4);           // gemm steal counters (layer1, layer2)
  size_t zero_bytes = off;

  int* cursor  = (int*)alloc((size_t)NR * (NN + 1) * 4);
  int* blocksum = (int*)alloc((size_t)NR * SCAN_NB * 4);
  float* n_dst = (float*)alloc((size_t)NR * NN * 4);
  int* rowptr  = (int*)alloc((size_t)NR * (NN + 1) * 4);
  int2* csr_e  = (int2*)alloc((size_t)NR * NE * 8);
  unsigned short* wt1 = (unsigned short*)alloc((size_t)NF * NK * 2);
  unsigned short* wt2 = (unsigned short*)alloc((size_t)NF * NK * 2);
  float* bs1 = (float*)alloc(NF * 4);
  float* bs2 = (float*)alloc(NF * 4);
  unsigned short* featbf = (unsigned short*)alloc((size_t)NN * NF * 2);
  unsigned short* h1 = (unsigned short*)alloc((size_t)NN * NF * 2);
  unsigned short* h2 = (unsigned short*)alloc((size_t)NN * NF * 2);
  unsigned short* agg = (unsigned short*)alloc((size_t)NN * NK * 2);
  (void)ws_size; (void)in_sizes; (void)n_in; (void)out_size;

  hipMemsetAsync(d_ws, 0, zero_bytes, stream);

  dim3 eg((NE + 255) / 256, NR);
  degree_kernel<<<eg, 256, 0, stream>>>(src, dst, deg_out, deg_in);
  scan_phaseA<<<dim3(SCAN_NB, NR), 256, 0, stream>>>(deg_in, blocksum);
  scan_phaseB<<<NR, 128, 0, stream>>>(blocksum, rowptr);
  scan_phaseC<<<dim3(SCAN_NB, NR), 256, 0, stream>>>(deg_in, blocksum, rowptr, cursor, n_dst);
  scatter_kernel<<<eg, 256, 0, stream>>>(src, dst, cursor, deg_out, csr_e);

  prep_w_kernel<<<dim3(16, NR, 2), 256, 0, stream>>>(W1, W2, b1, b2, wt1, wt2, bs1, bs2);
  cast_kernel<<<(NN * NF / 4 + 255) / 256, 256, 0, stream>>>(feat, featbf, NN * NF / 4);

  // layer 1
  spmm_kernel<<<(NN + 3) / 4, 256, 0, stream>>>(featbf, rowptr, csr_e, n_dst, agg);
  gemm_kernel<<<512, 256, 0, stream>>>(agg, wt1, bs1, h1, NN, 1, tilectr);
  // layer 2
  spmm_kernel<<<(NN + 3) / 4, 256, 0, stream>>>(h1, rowptr, csr_e, n_dst, agg);
  gemm_kernel<<<512, 256, 0, stream>>>(agg, wt2, bs2, h2, NN, 0, tilectr + 1);
  // pooling (direct, no atomics, includes divide)
  pool_kernel<<<NG, 256, 0, stream>>>(h2, gid, out);
}

// Round 17
// 693.738 us; speedup vs baseline: 1.0918x; 1.0918x over previous
//
#include <hip/hip_runtime.h>
#include <stdint.h>

#define NN 100000   // nodes
#define NE 400000   // edges per relation
#define NR 3        // relations
#define NF 256      // feature dim
#define NK 768      // NR*NF concatenated K
#define NG 128      // graphs
#define SCAN_NB ((NN + 1023) / 1024)   // 98 chunks of 1024
#define NT_GEMM ((NN + 127) / 128)     // 782 row-tiles

typedef __attribute__((ext_vector_type(4))) unsigned short ushortx4;
typedef __attribute__((ext_vector_type(8))) unsigned short ushortx8;
typedef __attribute__((ext_vector_type(8))) short short8;
typedef __attribute__((ext_vector_type(4))) float floatx4;

static __device__ __forceinline__ unsigned short f2bfu(float f) {
  union { float f; uint32_t u; } c; c.f = f;
  uint32_t x = c.u;
  uint32_t r = (x + 0x7fffu + ((x >> 16) & 1u)) >> 16;
  return (unsigned short)r;
}
static __device__ __forceinline__ float bfu2f(unsigned short u) {
  union { uint32_t u; float f; } c; c.u = ((uint32_t)u) << 16;
  return c.f;
}

static __device__ __forceinline__ void gload16(const void* g, void* l) {
  __builtin_amdgcn_global_load_lds(
      (const __attribute__((address_space(1))) uint32_t*)g,
      (__attribute__((address_space(3))) uint32_t*)l, 16, 0, 0);
}

// ---------------- graph preprocessing ----------------

__global__ __launch_bounds__(256) void degree_kernel(
    const int* __restrict__ src, const int* __restrict__ dst,
    int* __restrict__ deg_out, int* __restrict__ deg_in) {
  int t = blockIdx.x * 256 + threadIdx.x;
  int r = blockIdx.y;
  if (t < NE) {
    atomicAdd(&deg_out[r * NN + src[r * NE + t]], 1);
    atomicAdd(&deg_in[r * NN + dst[r * NE + t]], 1);
  }
}

// ---- multi-block exclusive scan of deg_in -> rowptr (3 phases) ----

__global__ __launch_bounds__(256) void scan_phaseA(
    const int* __restrict__ deg_in, int* __restrict__ blocksum) {
  int r = blockIdx.y, b = blockIdx.x, tid = threadIdx.x;
  const int* deg = deg_in + (size_t)r * NN;
  int base = b * 1024 + tid * 4;
  int s = 0;
#pragma unroll
  for (int i = 0; i < 4; ++i) { int idx = base + i; if (idx < NN) s += deg[idx]; }
  __shared__ int red[256];
  red[tid] = s; __syncthreads();
  for (int off = 128; off > 0; off >>= 1) {
    if (tid < off) red[tid] += red[tid + off];
    __syncthreads();
  }
  if (tid == 0) blocksum[r * SCAN_NB + b] = red[0];
}

__global__ __launch_bounds__(128) void scan_phaseB(
    int* __restrict__ blocksum, int* __restrict__ rowptr) {
  int r = blockIdx.x, tid = threadIdx.x;
  int* bs = blocksum + r * SCAN_NB;
  __shared__ int buf[128];
  int v = (tid < SCAN_NB) ? bs[tid] : 0;
  buf[tid] = v; __syncthreads();
  for (int off = 1; off < 128; off <<= 1) {
    int t = (tid >= off) ? buf[tid - off] : 0;
    __syncthreads();
    buf[tid] += t;
    __syncthreads();
  }
  if (tid < SCAN_NB) bs[tid] = buf[tid] - v;   // exclusive chunk offset
  if (tid == 127) rowptr[(size_t)r * (NN + 1) + NN] = buf[127];
}

// phaseC emits rowptr, cursor (copy), and n_dst in one pass
__global__ __launch_bounds__(256) void scan_phaseC(
    const int* __restrict__ deg_in, const int* __restrict__ blocksum,
    int* __restrict__ rowptr, int* __restrict__ cursor,
    float* __restrict__ n_dst) {
  int r = blockIdx.y, b = blockIdx.x, tid = threadIdx.x;
  const int* deg = deg_in + (size_t)r * NN;
  int* rp = rowptr + (size_t)r * (NN + 1);
  int* cp = cursor + (size_t)r * (NN + 1);
  int base = b * 1024 + tid * 4;
  int v[4]; int s = 0;
#pragma unroll
  for (int i = 0; i < 4; ++i) { int idx = base + i; v[i] = (idx < NN) ? deg[idx] : 0; s += v[i]; }
  __shared__ int buf[256];
  buf[tid] = s; __syncthreads();
  for (int off = 1; off < 256; off <<= 1) {
    int t = (tid >= off) ? buf[tid - off] : 0;
    __syncthreads();
    buf[tid] += t;
    __syncthreads();
  }
  int excl = buf[tid] - s + blocksum[r * SCAN_NB + b];
#pragma unroll
  for (int i = 0; i < 4; ++i) {
    int idx = base + i;
    if (idx < NN) {
      rp[idx] = excl;
      cp[idx] = excl;
      n_dst[(size_t)r * NN + idx] = v[i] > 0 ? rsqrtf((float)v[i]) : 0.f;
    }
    excl += v[i];
  }
}

// cursor pre-seeded with rowptr; atomicAdd gives the absolute CSR slot.
// n_src computed on the fly from deg_out (deg_out[s] >= 1 by construction).
__global__ __launch_bounds__(256) void scatter_kernel(
    const int* __restrict__ src, const int* __restrict__ dst,
    int* __restrict__ cursor, const int* __restrict__ deg_out,
    int2* __restrict__ csr_e) {
  int t = blockIdx.x * 256 + threadIdx.x;
  int r = blockIdx.y;
  if (t < NE) {
    int s = src[r * NE + t], v = dst[r * NE + t];
    int pos = atomicAdd(&cursor[r * (NN + 1) + v], 1);   // absolute within relation
    float w = rsqrtf((float)deg_out[r * NN + s]);
    csr_e[(size_t)r * NE + pos] = make_int2(s, __float_as_int(w));
  }
}

// ---------------- weight / feature prep ----------------

// Tiled LDS transpose: W[lay][r][k][n] (f32) -> wt[lay][n][r*256+k] (bf16).
// Also folds the bias sum (bs = b0+b1+b2) into the (tile 0, r 0) blocks.
__global__ __launch_bounds__(256) void prep_w_kernel(
    const float* __restrict__ W1, const float* __restrict__ W2,
    const float* __restrict__ b1, const float* __restrict__ b2,
    unsigned short* __restrict__ wt1, unsigned short* __restrict__ wt2,
    float* __restrict__ bs1, float* __restrict__ bs2) {
  __shared__ float lds[64][65];
  const int tile = blockIdx.x;          // 0..15: (kt,nt) 4x4
  const int r = blockIdx.y;             // 0..2
  const int lay = blockIdx.z;           // 0..1
  const float* W = lay ? W2 : W1;
  unsigned short* wt = lay ? wt2 : wt1;
  const int k0 = (tile >> 2) * 64, n0 = (tile & 3) * 64;
  const int ty = threadIdx.x >> 6;      // 0..3
  const int tx = threadIdx.x & 63;      // 0..63

  if (tile == 0 && r == 0) {            // fused bias sum (one block per layer)
    const float* b = lay ? b2 : b1;
    float* bs = lay ? bs2 : bs1;
    int t = threadIdx.x;
    bs[t] = b[t] + b[NF + t] + b[2 * NF + t];
  }

#pragma unroll
  for (int i = 0; i < 16; ++i) {
    int kl = ty * 16 + i;               // local k row
    lds[kl][tx] = W[((size_t)r * NF + k0 + kl) * NF + n0 + tx];  // coalesced over tx
  }
  __syncthreads();
#pragma unroll
  for (int i = 0; i < 16; ++i) {
    int nl = ty * 16 + i;               // local n row
    wt[(size_t)(n0 + nl) * NK + r * NF + k0 + tx] = f2bfu(lds[tx][nl]);
  }
}

// NT load: feat is read exactly once.
__global__ __launch_bounds__(256) void cast_kernel(
    const float* __restrict__ in, unsigned short* __restrict__ out, int n4) {
  int t = blockIdx.x * 256 + threadIdx.x;
  if (t < n4) {
    floatx4 v = __builtin_nontemporal_load((const floatx4*)&in[(size_t)t * 4]);
    ushortx4 o;
    o.x = f2bfu(v.x); o.y = f2bfu(v.y); o.z = f2bfu(v.z); o.w = f2bfu(v.w);
    *(ushortx4*)&out[(size_t)t * 4] = o;
  }
}

// ---------------- SpMM: one wave per NODE, 3 relations interleaved ----------------
// csr-entry PREFETCH (2-deep). Store phase: lanes 0-31, ushortx8, all indices
// compile-time constant (rule #20: no runtime-indexed register arrays).

__global__ __launch_bounds__(256) void spmm_kernel(
    const unsigned short* __restrict__ x,   // [NN][256] bf16
    const int* __restrict__ rowptr, const int2* __restrict__ csr_e,
    const float* __restrict__ n_dst,
    unsigned short* __restrict__ agg) {     // [NN][768] bf16
  int wid = threadIdx.x >> 6, l = threadIdx.x & 63;
  int v = blockIdx.x * 4 + wid;
  if (v >= NN) return;
  const int half = l >> 5;        // 0: edge e, 1: edge e+1
  const int c8 = (l & 31) * 8;    // this lane's 8-col strip

  int ea = rowptr[v],                e1a = rowptr[v + 1];
  int eb = rowptr[(NN + 1) + v],     e1b = rowptr[(NN + 1) + v + 1];
  int ec = rowptr[2 * (NN + 1) + v], e1c = rowptr[2 * (NN + 1) + v + 1];
  const int2* cea = csr_e;
  const int2* ceb = csr_e + (size_t)NE;
  const int2* cec = csr_e + (size_t)2 * NE;

  float a[NR][8];
#pragma unroll
  for (int r = 0; r < NR; ++r)
#pragma unroll
    for (int j = 0; j < 8; ++j) a[r][j] = 0.f;

  int2 qa = make_int2(0, 0), qb = make_int2(0, 0), qc = make_int2(0, 0);
  if (ea + half < e1a) qa = cea[ea + half];
  if (eb + half < e1b) qb = ceb[eb + half];
  if (ec + half < e1c) qc = cec[ec + half];

  while (ea < e1a || eb < e1b || ec < e1c) {
    int2 na = make_int2(0, 0), nb = make_int2(0, 0), nc = make_int2(0, 0);
    if (ea + 2 + half < e1a) na = cea[ea + 2 + half];
    if (eb + 2 + half < e1b) nb = ceb[eb + 2 + half];
    if (ec + 2 + half < e1c) nc = cec[ec + 2 + half];

    if (ea < e1a) {
      if (ea + half < e1a) {
        float w = __int_as_float(qa.y);
        ushortx8 xv = *(const ushortx8*)&x[(size_t)qa.x * NF + c8];
#pragma unroll
        for (int j = 0; j < 8; ++j) a[0][j] += w * bfu2f(xv[j]);
      }
      ea += 2; qa = na;
    }
    if (eb < e1b) {
      if (eb + half < e1b) {
        float w = __int_as_float(qb.y);
        ushortx8 xv = *(const ushortx8*)&x[(size_t)qb.x * NF + c8];
#pragma unroll
        for (int j = 0; j < 8; ++j) a[1][j] += w * bfu2f(xv[j]);
      }
      eb += 2; qb = nb;
    }
    if (ec < e1c) {
      if (ec + half < e1c) {
        float w = __int_as_float(qc.y);
        ushortx8 xv = *(const ushortx8*)&x[(size_t)qc.x * NF + c8];
#pragma unroll
        for (int j = 0; j < 8; ++j) a[2][j] += w * bfu2f(xv[j]);
      }
      ec += 2; qc = nc;
    }
  }

#pragma unroll
  for (int r = 0; r < NR; ++r)
#pragma unroll
    for (int j = 0; j < 8; ++j) a[r][j] += __shfl_xor(a[r][j], 32);

  if (l < 32) {
#pragma unroll
    for (int r = 0; r < NR; ++r) {
      float nd = n_dst[r * NN + v];
      ushortx8 o;
#pragma unroll
      for (int j = 0; j < 8; ++j) o[j] = f2bfu(a[r][j] * nd);
      *(ushortx8*)&agg[(size_t)v * NK + r * NF + c8] = o;
    }
  }
}

// ---------------- GEMM: persistent blocks + tile stealing, counted-vmcnt pipeline ----------------

__global__ __launch_bounds__(256, 2) void gemm_kernel(
    const unsigned short* __restrict__ A,    // [M][768] bf16
    const unsigned short* __restrict__ Bt,   // [256][768] bf16 (B^T: [col][K])
    const float* __restrict__ bias,          // [256]
    unsigned short* __restrict__ C,          // [M][256] bf16
    int M, int relu, int* __restrict__ tilectr) {
  __shared__ unsigned short ldsA[3][128 * 32];   // 24KB
  __shared__ unsigned short ldsB[2][256 * 32];   // 32KB
  __shared__ int s_tile;
  const int tid = threadIdx.x;
  const int l = tid & 63, wid = tid >> 6;
  const int c0 = wid * 64;                    // wave's 64-col strip
  const int fr = l & 15, fk = (l >> 4) * 8;
  const int NKT = NK / 32;                    // 24

  for (;;) {
    if (tid == 0) s_tile = atomicAdd(tilectr, 1);
    __syncthreads();
    const int tile = s_tile;
    if (tile >= NT_GEMM) return;              // uniform exit
    const int row0 = tile * 128;

    floatx4 acc[8][4];
#pragma unroll
    for (int i = 0; i < 8; ++i)
#pragma unroll
      for (int j = 0; j < 4; ++j)
#pragma unroll
        for (int q = 0; q < 4; ++q) acc[i][j][q] = 0.f;

    auto stageA = [&](int b, int kt) {
      const int k0 = kt * 32;
      int u = wid * 64 + l;                   // units 0..255
      int arow = row0 + (u >> 2);
      if (arow >= M) arow = M - 1;
      gload16(A + (size_t)arow * NK + k0 + (u & 3) * 8, &ldsA[b][u * 8]);
      u += 256;                               // units 256..511
      arow = row0 + (u >> 2);
      if (arow >= M) arow = M - 1;
      gload16(A + (size_t)arow * NK + k0 + (u & 3) * 8, &ldsA[b][u * 8]);
    };
    auto stageB = [&](int b, int kt) {
      const int k0 = kt * 32;
#pragma unroll
      for (int p = 0; p < 4; ++p) {           // 1024 units
        int uu = p * 256 + wid * 64 + l;
        gload16(Bt + (size_t)(uu >> 2) * NK + k0 + (uu & 3) * 8, &ldsB[b][uu * 8]);
      }
    };

    // prologue: B(0) [4 loads], A(0) [2], A(1) [2] -> 8 outstanding
    stageB(0, 0);
    stageA(0, 0);
    stageA(1, 1);

    for (int kt = 0; kt < NKT; ++kt) {
      if (kt < NKT - 1) {
        asm volatile("s_waitcnt vmcnt(2)" ::: "memory");
      } else {
        asm volatile("s_waitcnt vmcnt(0)" ::: "memory");
      }
      __builtin_amdgcn_s_barrier();
      __builtin_amdgcn_sched_barrier(0);

      if (kt + 1 < NKT) stageB((kt + 1) & 1, kt + 1);
      if (kt + 2 < NKT) stageA((kt + 2) % 3, kt + 2);
      __builtin_amdgcn_sched_barrier(0);

      const int ba = kt % 3, bb = kt & 1;
      short8 af[8], bf[4];
#pragma unroll
      for (int m = 0; m < 8; ++m)
        af[m] = *(const short8*)&ldsA[ba][(m * 16 + fr) * 32 + fk];
#pragma unroll
      for (int n = 0; n < 4; ++n)
        bf[n] = *(const short8*)&ldsB[bb][(c0 + n * 16 + fr) * 32 + fk];
#pragma unroll
      for (int m = 0; m < 8; ++m)
#pragma unroll
        for (int n = 0; n < 4; ++n)
          acc[m][n] = __builtin_amdgcn_mfma_f32_16x16x32_bf16(af[m], bf[n], acc[m][n], 0, 0, 0);
    }

    const int fq = l >> 4;
#pragma unroll
    for (int m = 0; m < 8; ++m) {
#pragma unroll
      for (int n = 0; n < 4; ++n) {
        int col = c0 + n * 16 + fr;
        float bv = bias[col];
#pragma unroll
        for (int q = 0; q < 4; ++q) {
          int row = row0 + m * 16 + fq * 4 + q;
          if (row < M) {
            float vv = acc[m][n][q] + bv;
            if (relu) vv = fmaxf(vv, 0.f);
            C[(size_t)row * NF + col] = f2bfu(vv);
          }
        }
      }
    }
    __syncthreads();   // all LDS reads done before next tile's stages / s_tile update
  }
}

// ---------------- pooling: one block per graph, no atomics ----------------

__global__ __launch_bounds__(256) void pool_kernel(
    const unsigned short* __restrict__ h2, const int* __restrict__ gid,
    float* __restrict__ out) {
  int g = blockIdx.x, c = threadIdx.x;
  int lo = 0, hi = NN;
  while (lo < hi) { int mid = (lo + hi) >> 1; if (gid[mid] < g) lo = mid + 1; else hi = mid; }
  int a = lo;
  lo = 0; hi = NN;
  while (lo < hi) { int mid = (lo + hi) >> 1; if (gid[mid] < g + 1) lo = mid + 1; else hi = mid; }
  int b = lo;
  float acc = 0.f;
  int v = a;
  for (; v + 4 <= b; v += 4) {
    float t0 = bfu2f(h2[(size_t)(v + 0) * NF + c]);
    float t1 = bfu2f(h2[(size_t)(v + 1) * NF + c]);
    float t2 = bfu2f(h2[(size_t)(v + 2) * NF + c]);
    float t3 = bfu2f(h2[(size_t)(v + 3) * NF + c]);
    acc += t0 + t1 + t2 + t3;
  }
  for (; v < b; ++v) acc += bfu2f(h2[(size_t)v * NF + c]);
  out[g * NF + c] = acc / fmaxf((float)(b - a), 1.f);
}

// ---------------- launch ----------------

extern "C" void kernel_launch(void* const* d_in, const int* in_sizes, int n_in,
                              void* d_out, int out_size, void* d_ws, size_t ws_size,
                              hipStream_t stream) {
  const float* feat = (const float*)d_in[0];
  const int* src = (const int*)d_in[1];
  const int* dst = (const int*)d_in[2];
  const int* gid = (const int*)d_in[3];
  const float* W1 = (const float*)d_in[4];
  const float* b1 = (const float*)d_in[5];
  const float* W2 = (const float*)d_in[6];
  const float* b2 = (const float*)d_in[7];
  float* out = (float*)d_out;

  char* ws = (char*)d_ws;
  size_t off = 0;
  auto alloc = [&](size_t bytes) -> void* {
    void* p = ws + off;
    off = (off + bytes + 255) & ~(size_t)255;
    return p;
  };

  // zero-initialized block (single memset)
  int* deg_out = (int*)alloc((size_t)NR * NN * 4);
  int* deg_in  = (int*)alloc((size_t)NR * NN * 4);
  int* tilectr = (int*)alloc(2 * 4);           // gemm steal counters (layer1, layer2)
  size_t zero_bytes = off;

  int* cursor  = (int*)alloc((size_t)NR * (NN + 1) * 4);
  int* blocksum = (int*)alloc((size_t)NR * SCAN_NB * 4);
  float* n_dst = (float*)alloc((size_t)NR * NN * 4);
  int* rowptr  = (int*)alloc((size_t)NR * (NN + 1) * 4);
  int2* csr_e  = (int2*)alloc((size_t)NR * NE * 8);
  unsigned short* wt1 = (unsigned short*)alloc((size_t)NF * NK * 2);
  unsigned short* wt2 = (unsigned short*)alloc((size_t)NF * NK * 2);
  float* bs1 = (float*)alloc(NF * 4);
  float* bs2 = (float*)alloc(NF * 4);
  unsigned short* featbf = (unsigned short*)alloc((size_t)NN * NF * 2);
  unsigned short* h1 = (unsigned short*)alloc((size_t)NN * NF * 2);
  unsigned short* h2 = (unsigned short*)alloc((size_t)NN * NF * 2);
  unsigned short* agg = (unsigned short*)alloc((size_t)NN * NK * 2);
  (void)ws_size; (void)in_sizes; (void)n_in; (void)out_size;

  hipMemsetAsync(d_ws, 0, zero_bytes, stream);

  dim3 eg((NE + 255) / 256, NR);
  degree_kernel<<<eg, 256, 0, stream>>>(src, dst, deg_out, deg_in);
  scan_phaseA<<<dim3(SCAN_NB, NR), 256, 0, stream>>>(deg_in, blocksum);
  scan_phaseB<<<NR, 128, 0, stream>>>(blocksum, rowptr);
  scan_phaseC<<<dim3(SCAN_NB, NR), 256, 0, stream>>>(deg_in, blocksum, rowptr, cursor, n_dst);
  scatter_kernel<<<eg, 256, 0, stream>>>(src, dst, cursor, deg_out, csr_e);

  prep_w_kernel<<<dim3(16, NR, 2), 256, 0, stream>>>(W1, W2, b1, b2, wt1, wt2, bs1, bs2);
  cast_kernel<<<(NN * NF / 4 + 255) / 256, 256, 0, stream>>>(feat, featbf, NN * NF / 4);

  // layer 1
  spmm_kernel<<<(NN + 3) / 4, 256, 0, stream>>>(featbf, rowptr, csr_e, n_dst, agg);
  gemm_kernel<<<512, 256, 0, stream>>>(agg, wt1, bs1, h1, NN, 1, tilectr);
  // layer 2
  spmm_kernel<<<(NN + 3) / 4, 256, 0, stream>>>(h1, rowptr, csr_e, n_dst, agg);
  gemm_kernel<<<512, 256, 0, stream>>>(agg, wt2, bs2, h2, NN, 0, tilectr + 1);
  // pooling (direct, no atomics, includes divide)
  pool_kernel<<<NG, 256, 0, stream>>>(h2, gid, out);
}